// Round 1
// baseline (1812.540 us; speedup 1.0000x reference)
//
#include <hip/hip_runtime.h>
#include <hip/hip_bf16.h>

typedef __attribute__((ext_vector_type(4))) float f32x4;
typedef __attribute__((ext_vector_type(4))) unsigned int u32x4;
typedef __attribute__((ext_vector_type(8))) __bf16 bf16x8;

#define DEV static __device__ __forceinline__

DEV unsigned short f2bf(float f) {
  unsigned u = __builtin_bit_cast(unsigned, f);
  u += 0x7fffu + ((u >> 16) & 1u);
  return (unsigned short)(u >> 16);
}
DEV float bf2f(unsigned short b) {
  return __builtin_bit_cast(float, ((unsigned)b) << 16);
}
DEV unsigned pk2(float a, float b) {
  return (unsigned)f2bf(a) | ((unsigned)f2bf(b) << 16);
}
DEV f32x4 mfma16(u32x4 a, u32x4 b, f32x4 c) {
  return __builtin_amdgcn_mfma_f32_16x16x32_bf16(
      __builtin_bit_cast(bf16x8, a), __builtin_bit_cast(bf16x8, b), c, 0, 0, 0);
}
DEV void unpack8(u32x4 c, float* f) {
#pragma unroll
  for (int e = 0; e < 4; e++) {
    f[e * 2]     = bf2f((unsigned short)(c[e] & 0xffffu));
    f[e * 2 + 1] = bf2f((unsigned short)(c[e] >> 16));
  }
}

// ---------------------------------------------------------------------------
// Generic GEMM: C[M][N] = A[M][K] * B[N][K]^T (+bias, epilogue variants)
// ASRC: 0 = gather fp32 x with shift/window reorder, 1 = linear bf16
// EPI:  0 = +bias -> bf16, 1 = +bias -> f32, 2 = +bias, gelu -> bf16
// ---------------------------------------------------------------------------
template <int ASRC, int EPI>
__global__ __launch_bounds__(256) void gemm_bt(
    const float* __restrict__ Ag, const unsigned short* __restrict__ Ab,
    const unsigned short* __restrict__ Bw, const float* __restrict__ bias,
    void* __restrict__ Cout, int M, int N, int K) {
  __shared__ __align__(16) unsigned short As[128 * 40];
  __shared__ __align__(16) unsigned short Bs[128 * 40];
  const int tid = threadIdx.x;
  const int m0 = blockIdx.x * 128, n0 = blockIdx.y * 128;
  const int srow = tid >> 1;
  const int kh = (tid & 1) << 4;

  const float* agp = nullptr;
  const unsigned short* abp = nullptr;
  if (ASRC == 0) {
    int m = m0 + srow;
    int w = m >> 6, t = m & 63;
    int b = w >> 6, wy = (w >> 3) & 7, wx = w & 7;
    int oy = (wy * 8 + (t >> 3) + 4) & 63;
    int ox = (wx * 8 + (t & 7) + 4) & 63;
    agp = Ag + (size_t)((((b << 6) | oy) << 6) | ox) * 384 + kh;
  } else {
    abp = Ab + (size_t)(m0 + srow) * K + kh;
  }
  const unsigned short* bbp = Bw + (size_t)(n0 + srow) * K + kh;
  unsigned short* adst = As + srow * 40 + kh;
  unsigned short* bdst = Bs + srow * 40 + kh;

  const int l = tid & 63;
  const int wv = tid >> 6;
  const int wm = (wv >> 1) << 6, wn = (wv & 1) << 6;
  const int lr = l & 15, lg = l >> 4;
  const unsigned short* arow = As + (wm + lr) * 40 + lg * 8;
  const unsigned short* brow = Bs + (wn + lr) * 40 + lg * 8;

  const f32x4 z4 = {0.f, 0.f, 0.f, 0.f};
  f32x4 acc[4][4];
#pragma unroll
  for (int i = 0; i < 4; i++)
#pragma unroll
    for (int j = 0; j < 4; j++) acc[i][j] = z4;

  for (int k0 = 0; k0 < K; k0 += 32) {
    __syncthreads();
    if (ASRC == 0) {
      const f32x4* sp = (const f32x4*)(agp + k0);
      f32x4 f0 = sp[0], f1 = sp[1], f2 = sp[2], f3 = sp[3];
      u32x4 o0 = {pk2(f0[0], f0[1]), pk2(f0[2], f0[3]), pk2(f1[0], f1[1]),
                  pk2(f1[2], f1[3])};
      u32x4 o1 = {pk2(f2[0], f2[1]), pk2(f2[2], f2[3]), pk2(f3[0], f3[1]),
                  pk2(f3[2], f3[3])};
      ((u32x4*)adst)[0] = o0;
      ((u32x4*)adst)[1] = o1;
    } else {
      const u32x4* sp = (const u32x4*)(abp + k0);
      ((u32x4*)adst)[0] = sp[0];
      ((u32x4*)adst)[1] = sp[1];
    }
    {
      const u32x4* sp = (const u32x4*)(bbp + k0);
      ((u32x4*)bdst)[0] = sp[0];
      ((u32x4*)bdst)[1] = sp[1];
    }
    __syncthreads();
    u32x4 a[4], b[4];
#pragma unroll
    for (int i = 0; i < 4; i++) a[i] = *(const u32x4*)(arow + i * 16 * 40);
#pragma unroll
    for (int j = 0; j < 4; j++) b[j] = *(const u32x4*)(brow + j * 16 * 40);
#pragma unroll
    for (int i = 0; i < 4; i++)
#pragma unroll
      for (int j = 0; j < 4; j++) acc[i][j] = mfma16(a[i], b[j], acc[i][j]);
  }

#pragma unroll
  for (int j = 0; j < 4; j++) {
    int ncol = n0 + wn + j * 16 + lr;
    float bv = bias[ncol];
#pragma unroll
    for (int i = 0; i < 4; i++) {
      int mbase = m0 + wm + i * 16 + lg * 4;
#pragma unroll
      for (int r = 0; r < 4; r++) {
        float v = acc[i][j][r] + bv;
        size_t off = (size_t)(mbase + r) * N + ncol;
        if (EPI == 2) v = 0.5f * v * (1.0f + erff(v * 0.70710678f));
        if (EPI == 1)
          ((float*)Cout)[off] = v;
        else
          ((unsigned short*)Cout)[off] = f2bf(v);
      }
    }
  }
}

// ---------------------------------------------------------------------------
// Per (window, head) cosine attention. 1 wave per block.
// qkv layout: [131072 rows (window-order)][1152] bf16, q|k|v at s*384 + h*32
// ---------------------------------------------------------------------------
__global__ __launch_bounds__(64) void attn_win(
    const unsigned short* __restrict__ qkv, const float* __restrict__ btab,
    const float* __restrict__ lscale, unsigned short* __restrict__ aout) {
  __shared__ __align__(16) unsigned short qs[64 * 40];
  __shared__ __align__(16) unsigned short ks[64 * 40];
  __shared__ __align__(16) unsigned short vT[32 * 72];
  __shared__ __align__(16) unsigned short Ps[64 * 72];
  const int w = blockIdx.x, h = blockIdx.y;
  const int t = threadIdx.x;
  const size_t rb = (size_t)(w * 64 + t) * 1152 + h * 32;

  // stage q (normalized), k (normalized), v (transposed)
  {
    const u32x4* qp = (const u32x4*)(qkv + rb);
    u32x4 c[4] = {qp[0], qp[1], qp[2], qp[3]};
    float f[32];
#pragma unroll
    for (int c4 = 0; c4 < 4; c4++) unpack8(c[c4], f + c4 * 8);
    float ssq = 0.f;
#pragma unroll
    for (int d = 0; d < 32; d++) ssq += f[d] * f[d];
    float rn = 1.f / fmaxf(sqrtf(ssq), 1e-12f);
    u32x4* qd = (u32x4*)(qs + t * 40);
#pragma unroll
    for (int c4 = 0; c4 < 4; c4++) {
      u32x4 o;
#pragma unroll
      for (int e = 0; e < 4; e++)
        o[e] = pk2(f[c4 * 8 + e * 2] * rn, f[c4 * 8 + e * 2 + 1] * rn);
      qd[c4] = o;
    }
  }
  {
    const u32x4* kp = (const u32x4*)(qkv + rb + 384);
    u32x4 c[4] = {kp[0], kp[1], kp[2], kp[3]};
    float f[32];
#pragma unroll
    for (int c4 = 0; c4 < 4; c4++) unpack8(c[c4], f + c4 * 8);
    float ssq = 0.f;
#pragma unroll
    for (int d = 0; d < 32; d++) ssq += f[d] * f[d];
    float rn = 1.f / fmaxf(sqrtf(ssq), 1e-12f);
    u32x4* kd = (u32x4*)(ks + t * 40);
#pragma unroll
    for (int c4 = 0; c4 < 4; c4++) {
      u32x4 o;
#pragma unroll
      for (int e = 0; e < 4; e++)
        o[e] = pk2(f[c4 * 8 + e * 2] * rn, f[c4 * 8 + e * 2 + 1] * rn);
      kd[c4] = o;
    }
  }
  {
    const u32x4* vp = (const u32x4*)(qkv + rb + 768);
#pragma unroll
    for (int c4 = 0; c4 < 4; c4++) {
      u32x4 c = vp[c4];
#pragma unroll
      for (int e = 0; e < 4; e++) {
        vT[(c4 * 8 + e * 2) * 72 + t] = (unsigned short)(c[e] & 0xffffu);
        vT[(c4 * 8 + e * 2 + 1) * 72 + t] = (unsigned short)(c[e] >> 16);
      }
    }
  }
  __syncthreads();

  const int lr = t & 15, lg = t >> 4;
  const f32x4 z4 = {0.f, 0.f, 0.f, 0.f};
  u32x4 bk[4];
#pragma unroll
  for (int tj = 0; tj < 4; tj++)
    bk[tj] = *(const u32x4*)(ks + (tj * 16 + lr) * 40 + lg * 8);
  f32x4 s[4][4];
#pragma unroll
  for (int ti = 0; ti < 4; ti++) {
    u32x4 aq = *(const u32x4*)(qs + (ti * 16 + lr) * 40 + lg * 8);
#pragma unroll
    for (int tj = 0; tj < 4; tj++) s[ti][tj] = mfma16(aq, bk[tj], z4);
  }

  float scl = expf(fminf(lscale[h], 4.6051702f));
  int wy = (w >> 3) & 7, wx = w & 7;
  float rden[4][4];
#pragma unroll
  for (int ti = 0; ti < 4; ti++) {
#pragma unroll
    for (int r = 0; r < 4; r++) {
      int q = ti * 16 + lg * 4 + r;
      int syq = wy * 8 + (q >> 3), sxq = wx * 8 + (q & 7);
      int rq = (syq < 56 ? 0 : (syq < 60 ? 1 : 2)) * 3 +
               (sxq < 56 ? 0 : (sxq < 60 ? 1 : 2));
      float vmax = -1e30f;
#pragma unroll
      for (int tj = 0; tj < 4; tj++) {
        int kk = tj * 16 + lr;
        int syk = wy * 8 + (kk >> 3), sxk = wx * 8 + (kk & 7);
        int rk = (syk < 56 ? 0 : (syk < 60 ? 1 : 2)) * 3 +
                 (sxk < 56 ? 0 : (sxk < 60 ? 1 : 2));
        float val = s[ti][tj][r] * scl + btab[(h << 12) + (q << 6) + kk] +
                    (rq != rk ? -100.f : 0.f);
        s[ti][tj][r] = val;
        vmax = fmaxf(vmax, val);
      }
#pragma unroll
      for (int d = 1; d < 16; d <<= 1) vmax = fmaxf(vmax, __shfl_xor(vmax, d, 64));
      float sum = 0.f;
#pragma unroll
      for (int tj = 0; tj < 4; tj++) {
        float p = expf(s[ti][tj][r] - vmax);
        s[ti][tj][r] = p;
        sum += p;
      }
#pragma unroll
      for (int d = 1; d < 16; d <<= 1) sum += __shfl_xor(sum, d, 64);
      rden[ti][r] = 1.f / sum;
#pragma unroll
      for (int tj = 0; tj < 4; tj++)
        Ps[q * 72 + tj * 16 + lr] = f2bf(s[ti][tj][r]);
    }
  }
  __syncthreads();

  f32x4 o[4][2];
#pragma unroll
  for (int ti = 0; ti < 4; ti++)
#pragma unroll
    for (int tj2 = 0; tj2 < 2; tj2++) o[ti][tj2] = z4;
#pragma unroll
  for (int kc = 0; kc < 2; kc++) {
    u32x4 vb[2];
#pragma unroll
    for (int tj2 = 0; tj2 < 2; tj2++)
      vb[tj2] = *(const u32x4*)(vT + (tj2 * 16 + lr) * 72 + kc * 32 + lg * 8);
#pragma unroll
    for (int ti = 0; ti < 4; ti++) {
      u32x4 pa = *(const u32x4*)(Ps + (ti * 16 + lr) * 72 + kc * 32 + lg * 8);
#pragma unroll
      for (int tj2 = 0; tj2 < 2; tj2++)
        o[ti][tj2] = mfma16(pa, vb[tj2], o[ti][tj2]);
    }
  }
#pragma unroll
  for (int ti = 0; ti < 4; ti++)
#pragma unroll
    for (int tj2 = 0; tj2 < 2; tj2++)
#pragma unroll
      for (int r = 0; r < 4; r++) {
        int q = ti * 16 + lg * 4 + r;
        aout[(size_t)(w * 64 + q) * 384 + h * 32 + tj2 * 16 + lr] =
            f2bf(o[ti][tj2][r] * rden[ti][r]);
      }
}

// ---------------------------------------------------------------------------
// LN1: y1 = x + LN(proj_out gathered back through window-reverse + unshift)
// writes y1 (f32, d_out) and y1 bf16 (ws) for the MLP GEMM
// ---------------------------------------------------------------------------
__global__ __launch_bounds__(256) void ln1_kernel(
    const float* __restrict__ proj, const float* __restrict__ x,
    const float* __restrict__ nw, const float* __restrict__ nb,
    float* __restrict__ yout, unsigned short* __restrict__ y1b) {
  int wv = threadIdx.x >> 6, l = threadIdx.x & 63;
  int n = blockIdx.x * 4 + wv;
  int b = n >> 12, y = (n >> 6) & 63, xx = n & 63;
  int sy = (y + 60) & 63, sx = (xx + 60) & 63;
  int m = ((((b << 6) | ((sy >> 3) << 3) | (sx >> 3)) << 6) |
           ((sy & 7) << 3) | (sx & 7));
  const float* pr = proj + (size_t)m * 384;
  const float* xr = x + (size_t)n * 384;
  float v[6];
  float sum = 0.f, ssq = 0.f;
#pragma unroll
  for (int c = 0; c < 6; c++) {
    v[c] = pr[l + c * 64];
    sum += v[c];
    ssq += v[c] * v[c];
  }
#pragma unroll
  for (int d = 1; d < 64; d <<= 1) {
    sum += __shfl_xor(sum, d, 64);
    ssq += __shfl_xor(ssq, d, 64);
  }
  float mu = sum * (1.f / 384.f);
  float rstd = rsqrtf(ssq * (1.f / 384.f) - mu * mu + 1e-5f);
#pragma unroll
  for (int c = 0; c < 6; c++) {
    int i = l + c * 64;
    float o = (v[c] - mu) * rstd * nw[i] + nb[i];
    float yv = xr[i] + o;
    size_t off = (size_t)n * 384 + i;
    yout[off] = yv;
    y1b[off] = f2bf(yv);
  }
}

// LN2: out = y1 + LN(h2)   (in-place on d_out)
__global__ __launch_bounds__(256) void ln2_kernel(
    const float* __restrict__ h2, const float* __restrict__ nw,
    const float* __restrict__ nb, float* __restrict__ yio) {
  int wv = threadIdx.x >> 6, l = threadIdx.x & 63;
  int n = blockIdx.x * 4 + wv;
  const float* hr = h2 + (size_t)n * 384;
  float v[6];
  float sum = 0.f, ssq = 0.f;
#pragma unroll
  for (int c = 0; c < 6; c++) {
    v[c] = hr[l + c * 64];
    sum += v[c];
    ssq += v[c] * v[c];
  }
#pragma unroll
  for (int d = 1; d < 64; d <<= 1) {
    sum += __shfl_xor(sum, d, 64);
    ssq += __shfl_xor(ssq, d, 64);
  }
  float mu = sum * (1.f / 384.f);
  float rstd = rsqrtf(ssq * (1.f / 384.f) - mu * mu + 1e-5f);
#pragma unroll
  for (int c = 0; c < 6; c++) {
    int i = l + c * 64;
    float o = (v[c] - mu) * rstd * nw[i] + nb[i];
    size_t off = (size_t)n * 384 + i;
    yio[off] = yio[off] + o;
  }
}

// rel-pos bias table: btab[h][q][k], 12 x 64 x 64
__global__ __launch_bounds__(256) void btab_kernel(
    const float* __restrict__ w1, const float* __restrict__ b1,
    const float* __restrict__ w2, const float* __restrict__ b2,
    float* __restrict__ btab) {
  int p = blockIdx.x * 256 + threadIdx.x;
  int i = p >> 6, j = p & 63;
  float dy = (float)((i >> 3) - (j >> 3));
  float dx = (float)((i & 7) - (j & 7));
  float r0 = (dy > 0.f ? 1.f : (dy < 0.f ? -1.f : 0.f)) * log1pf(fabsf(dy));
  float r1 = (dx > 0.f ? 1.f : (dx < 0.f ? -1.f : 0.f)) * log1pf(fabsf(dx));
  float acc[12];
#pragma unroll
  for (int hh = 0; hh < 12; hh++) acc[hh] = b2[hh];
  for (int c = 0; c < 384; c++) {
    float hv = w1[c * 2] * r0 + w1[c * 2 + 1] * r1 + b1[c];
    hv = fmaxf(hv, 0.f);
#pragma unroll
    for (int hh = 0; hh < 12; hh++) acc[hh] += hv * w2[hh * 384 + c];
  }
#pragma unroll
  for (int hh = 0; hh < 12; hh++) btab[(hh << 12) + p] = acc[hh];
}

__global__ __launch_bounds__(256) void cvt_kernel(
    const float* __restrict__ s, unsigned short* __restrict__ d, int n) {
  int i = blockIdx.x * 256 + threadIdx.x;
  if (i < n) d[i] = f2bf(s[i]);
}

// ---------------------------------------------------------------------------
extern "C" void kernel_launch(void* const* d_in, const int* in_sizes, int n_in,
                              void* d_out, int out_size, void* d_ws,
                              size_t ws_size, hipStream_t stream) {
  (void)in_sizes; (void)n_in; (void)out_size; (void)ws_size;
  const float* x      = (const float*)d_in[0];
  const float* qkv_w  = (const float*)d_in[1];
  const float* qkv_b  = (const float*)d_in[2];
  const float* proj_w = (const float*)d_in[3];
  const float* proj_b = (const float*)d_in[4];
  const float* mw1    = (const float*)d_in[5];
  const float* mb1    = (const float*)d_in[6];
  const float* mw2    = (const float*)d_in[7];
  const float* mb2    = (const float*)d_in[8];
  const float* lsc    = (const float*)d_in[9];
  const float* n1w    = (const float*)d_in[10];
  const float* n1b    = (const float*)d_in[11];
  const float* w1     = (const float*)d_in[12];
  const float* b1     = (const float*)d_in[13];
  const float* w2     = (const float*)d_in[14];
  const float* b2     = (const float*)d_in[15];
  const float* n2w    = (const float*)d_in[16];
  const float* n2b    = (const float*)d_in[17];

  char* ws = (char*)d_ws;
  unsigned short* wqb = (unsigned short*)(ws + 0);
  unsigned short* wpb = (unsigned short*)(ws + 884736);
  unsigned short* w1b = (unsigned short*)(ws + 1179648);
  unsigned short* w2b = (unsigned short*)(ws + 2359296);
  float* btab         = (float*)(ws + 3538944);
  unsigned short* qkvb = (unsigned short*)(ws + 4194304);       // 302 MB
  unsigned short* att  = (unsigned short*)(ws + 306184192);     // 101 MB
  float* projo         = (float*)(ws + 406847488);              // 201 MB
  unsigned short* y1b  = att;    // reuse (att dead after proj GEMM)
  float* h2            = projo;  // reuse (projo dead after LN1)
  unsigned short* hb   = (unsigned short*)(ws + 608174080);     // 101 MB chunk
  float* yout = (float*)d_out;

  cvt_kernel<<<dim3(1728), 256, 0, stream>>>(qkv_w, wqb, 442368);
  cvt_kernel<<<dim3(576), 256, 0, stream>>>(proj_w, wpb, 147456);
  cvt_kernel<<<dim3(2304), 256, 0, stream>>>(w1, w1b, 589824);
  cvt_kernel<<<dim3(2304), 256, 0, stream>>>(w2, w2b, 589824);
  btab_kernel<<<dim3(16), 256, 0, stream>>>(mw1, mb1, mw2, mb2, btab);

  // QKV: gather + GEMM, 131072 x 1152 x 384
  gemm_bt<0, 0><<<dim3(1024, 9), 256, 0, stream>>>(
      x, nullptr, wqb, qkv_b, qkvb, 131072, 1152, 384);
  // attention per (window, head)
  attn_win<<<dim3(2048, 12), 64, 0, stream>>>(qkvb, btab, lsc, att);
  // proj: 131072 x 384 x 384 -> f32
  gemm_bt<1, 1><<<dim3(1024, 3), 256, 0, stream>>>(
      nullptr, att, wpb, proj_b, projo, 131072, 384, 384);
  // LN1 + residual (+ ungather)
  ln1_kernel<<<dim3(32768), 256, 0, stream>>>(projo, x, n1w, n1b, yout, y1b);
  // MLP, chunked over M (4 x 32768 rows)
  for (int c = 0; c < 4; c++) {
    const unsigned short* ya = y1b + (size_t)c * 32768 * 384;
    float* h2c = h2 + (size_t)c * 32768 * 384;
    gemm_bt<1, 2><<<dim3(256, 12), 256, 0, stream>>>(
        nullptr, ya, w1b, b1, hb, 32768, 1536, 384);
    gemm_bt<1, 1><<<dim3(256, 3), 256, 0, stream>>>(
        nullptr, hb, w2b, b2, h2c, 32768, 384, 1536);
  }
  // LN2 + residual
  ln2_kernel<<<dim3(32768), 256, 0, stream>>>(h2, n2w, n2b, yout);
}

// Round 2
// 1519.309 us; speedup vs baseline: 1.1930x; 1.1930x over previous
//
#include <hip/hip_runtime.h>
#include <hip/hip_bf16.h>

typedef __attribute__((ext_vector_type(4))) float f32x4;
typedef __attribute__((ext_vector_type(4))) unsigned int u32x4;
typedef __attribute__((ext_vector_type(8))) __bf16 bf16x8;
typedef unsigned short ushort_t;

#define DEV static __device__ __forceinline__

DEV unsigned short f2bf(float f) {
  unsigned u = __builtin_bit_cast(unsigned, f);
  u += 0x7fffu + ((u >> 16) & 1u);
  return (unsigned short)(u >> 16);
}
DEV float bf2f(unsigned short b) {
  return __builtin_bit_cast(float, ((unsigned)b) << 16);
}
DEV unsigned pk2(float a, float b) {
  return (unsigned)f2bf(a) | ((unsigned)f2bf(b) << 16);
}
DEV f32x4 mfma16(u32x4 a, u32x4 b, f32x4 c) {
  return __builtin_amdgcn_mfma_f32_16x16x32_bf16(
      __builtin_bit_cast(bf16x8, a), __builtin_bit_cast(bf16x8, b), c, 0, 0, 0);
}
DEV void unpack8(u32x4 c, float* f) {
#pragma unroll
  for (int e = 0; e < 4; e++) {
    f[e * 2]     = bf2f((unsigned short)(c[e] & 0xffffu));
    f[e * 2 + 1] = bf2f((unsigned short)(c[e] >> 16));
  }
}
DEV void gload16(const unsigned short* g, unsigned short* l) {
  __builtin_amdgcn_global_load_lds(
      (const __attribute__((address_space(1))) unsigned int*)g,
      (__attribute__((address_space(3))) unsigned int*)l, 16, 0, 0);
}

// ---------------------------------------------------------------------------
// bf16 GEMM: C[M][N] = A[M][K] * B[N][K]^T + bias.  EPI: 0 = bf16, 1 = gelu->bf16
// 128x128 tile, BK=32, 4 waves, global_load_lds staging with granule-XOR
// swizzle (LDS dest linear; global source pre-swizzled; reads swizzled).
// Requires: K%32==0, N%128==0, grid = mblocks*nblocks with grid%8==0.
// ---------------------------------------------------------------------------
template <int EPI>
__global__ __launch_bounds__(256) void gemm_lds(
    const unsigned short* __restrict__ A, const unsigned short* __restrict__ B,
    const float* __restrict__ bias, unsigned short* __restrict__ C,
    int N, int K, int mblocks) {
  __shared__ __align__(16) unsigned short As[128 * 32];
  __shared__ __align__(16) unsigned short Bs[128 * 32];
  const int nwg = gridDim.x;
  const int bid = blockIdx.x;
  const int swz = (bid & 7) * (nwg >> 3) + (bid >> 3);  // XCD-aware (nwg%8==0)
  const int m0 = (swz % mblocks) * 128;
  const int n0 = (swz / mblocks) * 128;

  const int tid = threadIdx.x;
  const int w = tid >> 6, l = tid & 63;
  // staging: lane l of wave w writes LDS bytes [it*4096 + w*1024 + l*16, +16)
  // -> row = it*64 + w*16 + (l>>2), granule = l&3.
  const int rs0 = w * 16 + (l >> 2);
  const int gs = (((l & 3) ^ ((rs0 >> 1) & 3)) * 8);  // pre-swizzled source col
  const unsigned short* a0 = A + (size_t)(m0 + rs0) * K + gs;
  const unsigned short* a1 = A + (size_t)(m0 + 64 + rs0) * K + gs;
  const unsigned short* b0 = B + (size_t)(n0 + rs0) * K + gs;
  const unsigned short* b1 = B + (size_t)(n0 + 64 + rs0) * K + gs;
  unsigned short* lA0 = As + w * 512;          // wave-uniform; HW adds lane*16
  unsigned short* lA1 = As + 2048 + w * 512;
  unsigned short* lB0 = Bs + w * 512;
  unsigned short* lB1 = Bs + 2048 + w * 512;

  const int wm = (w >> 1) << 6, wn = (w & 1) << 6;
  const int lr = l & 15, lg = l >> 4;
  const int swr = (lg ^ ((lr >> 1) & 3)) * 8;  // swizzled read granule
  const unsigned short* arow = As + (wm + lr) * 32 + swr;
  const unsigned short* brow = Bs + (wn + lr) * 32 + swr;

  const f32x4 z4 = {0.f, 0.f, 0.f, 0.f};
  f32x4 acc[4][4];
#pragma unroll
  for (int i = 0; i < 4; i++)
#pragma unroll
    for (int j = 0; j < 4; j++) acc[i][j] = z4;

  for (int k0 = 0; k0 < K; k0 += 32) {
    __syncthreads();  // previous compute done before overwriting LDS
    gload16(a0 + k0, lA0);
    gload16(a1 + k0, lA1);
    gload16(b0 + k0, lB0);
    gload16(b1 + k0, lB1);
    __syncthreads();  // compiler drains vmcnt before s_barrier
    u32x4 a[4], b[4];
#pragma unroll
    for (int i = 0; i < 4; i++) a[i] = *(const u32x4*)(arow + i * 16 * 32);
#pragma unroll
    for (int j = 0; j < 4; j++) b[j] = *(const u32x4*)(brow + j * 16 * 32);
#pragma unroll
    for (int i = 0; i < 4; i++)
#pragma unroll
      for (int j = 0; j < 4; j++) acc[i][j] = mfma16(a[i], b[j], acc[i][j]);
  }

#pragma unroll
  for (int j = 0; j < 4; j++) {
    int ncol = n0 + wn + j * 16 + lr;
    float bv = bias[ncol];
#pragma unroll
    for (int i = 0; i < 4; i++) {
      int mbase = m0 + wm + i * 16 + lg * 4;
#pragma unroll
      for (int r = 0; r < 4; r++) {
        float v = acc[i][j][r] + bv;
        if (EPI == 1) v = 0.5f * v * (1.0f + erff(v * 0.70710678f));
        C[(size_t)(mbase + r) * N + ncol] = f2bf(v);
      }
    }
  }
}

// ---------------------------------------------------------------------------
// shift + window gather + fp32->bf16:  xb[m][384] (window order)
// ---------------------------------------------------------------------------
__global__ __launch_bounds__(256) void gather_cvt(
    const float* __restrict__ x, unsigned short* __restrict__ xb) {
  int wv = threadIdx.x >> 6, l = threadIdx.x & 63;
  int m = blockIdx.x * 4 + wv;
  int w = m >> 6, t = m & 63;
  int b = w >> 6, wy = (w >> 3) & 7, wx = w & 7;
  int oy = (wy * 8 + (t >> 3) + 4) & 63;
  int ox = (wx * 8 + (t & 7) + 4) & 63;
  const float2* src =
      (const float2*)(x + (size_t)((((b << 6) | oy) << 6) | ox) * 384 + l * 6);
  float2 f0 = src[0], f1 = src[1], f2 = src[2];
  unsigned* dst = (unsigned*)(xb + (size_t)m * 384 + l * 6);
  dst[0] = pk2(f0.x, f0.y);
  dst[1] = pk2(f1.x, f1.y);
  dst[2] = pk2(f2.x, f2.y);
}

// ---------------------------------------------------------------------------
// Per (window, head) cosine attention. 1 wave per block.
// ---------------------------------------------------------------------------
__global__ __launch_bounds__(64) void attn_win(
    const unsigned short* __restrict__ qkv, const float* __restrict__ btab,
    const float* __restrict__ lscale, unsigned short* __restrict__ aout) {
  __shared__ __align__(16) unsigned short qs[64 * 40];
  __shared__ __align__(16) unsigned short ks[64 * 40];
  __shared__ __align__(16) unsigned short vT[32 * 72];
  __shared__ __align__(16) unsigned short Ps[64 * 72];
  const int w = blockIdx.x, h = blockIdx.y;
  const int t = threadIdx.x;
  const size_t rb = (size_t)(w * 64 + t) * 1152 + h * 32;

  {
    const u32x4* qp = (const u32x4*)(qkv + rb);
    u32x4 c[4] = {qp[0], qp[1], qp[2], qp[3]};
    float f[32];
#pragma unroll
    for (int c4 = 0; c4 < 4; c4++) unpack8(c[c4], f + c4 * 8);
    float ssq = 0.f;
#pragma unroll
    for (int d = 0; d < 32; d++) ssq += f[d] * f[d];
    float rn = 1.f / fmaxf(sqrtf(ssq), 1e-12f);
    u32x4* qd = (u32x4*)(qs + t * 40);
#pragma unroll
    for (int c4 = 0; c4 < 4; c4++) {
      u32x4 o;
#pragma unroll
      for (int e = 0; e < 4; e++)
        o[e] = pk2(f[c4 * 8 + e * 2] * rn, f[c4 * 8 + e * 2 + 1] * rn);
      qd[c4] = o;
    }
  }
  {
    const u32x4* kp = (const u32x4*)(qkv + rb + 384);
    u32x4 c[4] = {kp[0], kp[1], kp[2], kp[3]};
    float f[32];
#pragma unroll
    for (int c4 = 0; c4 < 4; c4++) unpack8(c[c4], f + c4 * 8);
    float ssq = 0.f;
#pragma unroll
    for (int d = 0; d < 32; d++) ssq += f[d] * f[d];
    float rn = 1.f / fmaxf(sqrtf(ssq), 1e-12f);
    u32x4* kd = (u32x4*)(ks + t * 40);
#pragma unroll
    for (int c4 = 0; c4 < 4; c4++) {
      u32x4 o;
#pragma unroll
      for (int e = 0; e < 4; e++)
        o[e] = pk2(f[c4 * 8 + e * 2] * rn, f[c4 * 8 + e * 2 + 1] * rn);
      kd[c4] = o;
    }
  }
  {
    const u32x4* vp = (const u32x4*)(qkv + rb + 768);
#pragma unroll
    for (int c4 = 0; c4 < 4; c4++) {
      u32x4 c = vp[c4];
#pragma unroll
      for (int e = 0; e < 4; e++) {
        vT[(c4 * 8 + e * 2) * 72 + t] = (unsigned short)(c[e] & 0xffffu);
        vT[(c4 * 8 + e * 2 + 1) * 72 + t] = (unsigned short)(c[e] >> 16);
      }
    }
  }
  __syncthreads();

  const int lr = t & 15, lg = t >> 4;
  const f32x4 z4 = {0.f, 0.f, 0.f, 0.f};
  u32x4 bk[4];
#pragma unroll
  for (int tj = 0; tj < 4; tj++)
    bk[tj] = *(const u32x4*)(ks + (tj * 16 + lr) * 40 + lg * 8);
  f32x4 s[4][4];
#pragma unroll
  for (int ti = 0; ti < 4; ti++) {
    u32x4 aq = *(const u32x4*)(qs + (ti * 16 + lr) * 40 + lg * 8);
#pragma unroll
    for (int tj = 0; tj < 4; tj++) s[ti][tj] = mfma16(aq, bk[tj], z4);
  }

  float scl = expf(fminf(lscale[h], 4.6051702f));
  int wy = (w >> 3) & 7, wx = w & 7;
  float rden[4][4];
#pragma unroll
  for (int ti = 0; ti < 4; ti++) {
#pragma unroll
    for (int r = 0; r < 4; r++) {
      int q = ti * 16 + lg * 4 + r;
      int syq = wy * 8 + (q >> 3), sxq = wx * 8 + (q & 7);
      int rq = (syq < 56 ? 0 : (syq < 60 ? 1 : 2)) * 3 +
               (sxq < 56 ? 0 : (sxq < 60 ? 1 : 2));
      float vmax = -1e30f;
#pragma unroll
      for (int tj = 0; tj < 4; tj++) {
        int kk = tj * 16 + lr;
        int syk = wy * 8 + (kk >> 3), sxk = wx * 8 + (kk & 7);
        int rk = (syk < 56 ? 0 : (syk < 60 ? 1 : 2)) * 3 +
                 (sxk < 56 ? 0 : (sxk < 60 ? 1 : 2));
        float val = s[ti][tj][r] * scl + btab[(h << 12) + (q << 6) + kk] +
                    (rq != rk ? -100.f : 0.f);
        s[ti][tj][r] = val;
        vmax = fmaxf(vmax, val);
      }
#pragma unroll
      for (int d = 1; d < 16; d <<= 1) vmax = fmaxf(vmax, __shfl_xor(vmax, d, 64));
      float sum = 0.f;
#pragma unroll
      for (int tj = 0; tj < 4; tj++) {
        float p = expf(s[ti][tj][r] - vmax);
        s[ti][tj][r] = p;
        sum += p;
      }
#pragma unroll
      for (int d = 1; d < 16; d <<= 1) sum += __shfl_xor(sum, d, 64);
      rden[ti][r] = 1.f / sum;
#pragma unroll
      for (int tj = 0; tj < 4; tj++)
        Ps[q * 72 + tj * 16 + lr] = f2bf(s[ti][tj][r]);
    }
  }
  __syncthreads();

  f32x4 o[4][2];
#pragma unroll
  for (int ti = 0; ti < 4; ti++)
#pragma unroll
    for (int tj2 = 0; tj2 < 2; tj2++) o[ti][tj2] = z4;
#pragma unroll
  for (int kc = 0; kc < 2; kc++) {
    u32x4 vb[2];
#pragma unroll
    for (int tj2 = 0; tj2 < 2; tj2++)
      vb[tj2] = *(const u32x4*)(vT + (tj2 * 16 + lr) * 72 + kc * 32 + lg * 8);
#pragma unroll
    for (int ti = 0; ti < 4; ti++) {
      u32x4 pa = *(const u32x4*)(Ps + (ti * 16 + lr) * 72 + kc * 32 + lg * 8);
#pragma unroll
      for (int tj2 = 0; tj2 < 2; tj2++)
        o[ti][tj2] = mfma16(pa, vb[tj2], o[ti][tj2]);
    }
  }
#pragma unroll
  for (int ti = 0; ti < 4; ti++)
#pragma unroll
    for (int tj2 = 0; tj2 < 2; tj2++)
#pragma unroll
      for (int r = 0; r < 4; r++) {
        int q = ti * 16 + lg * 4 + r;
        aout[(size_t)(w * 64 + q) * 384 + h * 32 + tj2 * 16 + lr] =
            f2bf(o[ti][tj2][r] * rden[ti][r]);
      }
}

// ---------------------------------------------------------------------------
// LN1: y1 = x + LN(proj bf16, window-reverse + unshift); yout f32, y1b bf16
// ---------------------------------------------------------------------------
__global__ __launch_bounds__(256) void ln1_kernel(
    const unsigned short* __restrict__ projb, const float* __restrict__ x,
    const float* __restrict__ nw, const float* __restrict__ nb,
    float* __restrict__ yout, unsigned short* __restrict__ y1b) {
  int wv = threadIdx.x >> 6, l = threadIdx.x & 63;
  int n = blockIdx.x * 4 + wv;
  int b = n >> 12, y = (n >> 6) & 63, xx = n & 63;
  int sy = (y + 60) & 63, sx = (xx + 60) & 63;
  int m = ((((b << 6) | ((sy >> 3) << 3) | (sx >> 3)) << 6) |
           ((sy & 7) << 3) | (sx & 7));
  const unsigned* pr = (const unsigned*)(projb + (size_t)m * 384 + l * 6);
  unsigned u0 = pr[0], u1 = pr[1], u2 = pr[2];
  float v[6] = {bf2f((unsigned short)(u0 & 0xffffu)), bf2f((unsigned short)(u0 >> 16)),
                bf2f((unsigned short)(u1 & 0xffffu)), bf2f((unsigned short)(u1 >> 16)),
                bf2f((unsigned short)(u2 & 0xffffu)), bf2f((unsigned short)(u2 >> 16))};
  float sum = 0.f, ssq = 0.f;
#pragma unroll
  for (int c = 0; c < 6; c++) { sum += v[c]; ssq += v[c] * v[c]; }
#pragma unroll
  for (int d = 1; d < 64; d <<= 1) {
    sum += __shfl_xor(sum, d, 64);
    ssq += __shfl_xor(ssq, d, 64);
  }
  float mu = sum * (1.f / 384.f);
  float rstd = rsqrtf(ssq * (1.f / 384.f) - mu * mu + 1e-5f);
  const float2* xr = (const float2*)(x + (size_t)n * 384 + l * 6);
  float2 x0 = xr[0], x1 = xr[1], x2 = xr[2];
  float xv[6] = {x0.x, x0.y, x1.x, x1.y, x2.x, x2.y};
  float o[6];
#pragma unroll
  for (int c = 0; c < 6; c++) {
    int i = l * 6 + c;
    o[c] = xv[c] + (v[c] - mu) * rstd * nw[i] + nb[i];
  }
  float2* yo = (float2*)(yout + (size_t)n * 384 + l * 6);
  yo[0] = make_float2(o[0], o[1]);
  yo[1] = make_float2(o[2], o[3]);
  yo[2] = make_float2(o[4], o[5]);
  unsigned* yb = (unsigned*)(y1b + (size_t)n * 384 + l * 6);
  yb[0] = pk2(o[0], o[1]);
  yb[1] = pk2(o[2], o[3]);
  yb[2] = pk2(o[4], o[5]);
}

// LN2: out = y1 + LN(h2 bf16)   (in-place on d_out)
__global__ __launch_bounds__(256) void ln2_kernel(
    const unsigned short* __restrict__ h2b, const float* __restrict__ nw,
    const float* __restrict__ nb, float* __restrict__ yio) {
  int wv = threadIdx.x >> 6, l = threadIdx.x & 63;
  int n = blockIdx.x * 4 + wv;
  const unsigned* hr = (const unsigned*)(h2b + (size_t)n * 384 + l * 6);
  unsigned u0 = hr[0], u1 = hr[1], u2 = hr[2];
  float v[6] = {bf2f((unsigned short)(u0 & 0xffffu)), bf2f((unsigned short)(u0 >> 16)),
                bf2f((unsigned short)(u1 & 0xffffu)), bf2f((unsigned short)(u1 >> 16)),
                bf2f((unsigned short)(u2 & 0xffffu)), bf2f((unsigned short)(u2 >> 16))};
  float sum = 0.f, ssq = 0.f;
#pragma unroll
  for (int c = 0; c < 6; c++) { sum += v[c]; ssq += v[c] * v[c]; }
#pragma unroll
  for (int d = 1; d < 64; d <<= 1) {
    sum += __shfl_xor(sum, d, 64);
    ssq += __shfl_xor(ssq, d, 64);
  }
  float mu = sum * (1.f / 384.f);
  float rstd = rsqrtf(ssq * (1.f / 384.f) - mu * mu + 1e-5f);
  float2* yo = (float2*)(yio + (size_t)n * 384 + l * 6);
  float2 y0 = yo[0], y1 = yo[1], y2 = yo[2];
  float yv[6] = {y0.x, y0.y, y1.x, y1.y, y2.x, y2.y};
#pragma unroll
  for (int c = 0; c < 6; c++) {
    int i = l * 6 + c;
    yv[c] += (v[c] - mu) * rstd * nw[i] + nb[i];
  }
  yo[0] = make_float2(yv[0], yv[1]);
  yo[1] = make_float2(yv[2], yv[3]);
  yo[2] = make_float2(yv[4], yv[5]);
}

// rel-pos bias table: btab[h][q][k], 12 x 64 x 64
__global__ __launch_bounds__(256) void btab_kernel(
    const float* __restrict__ w1, const float* __restrict__ b1,
    const float* __restrict__ w2, const float* __restrict__ b2,
    float* __restrict__ btab) {
  int p = blockIdx.x * 256 + threadIdx.x;
  int i = p >> 6, j = p & 63;
  float dy = (float)((i >> 3) - (j >> 3));
  float dx = (float)((i & 7) - (j & 7));
  float r0 = (dy > 0.f ? 1.f : (dy < 0.f ? -1.f : 0.f)) * log1pf(fabsf(dy));
  float r1 = (dx > 0.f ? 1.f : (dx < 0.f ? -1.f : 0.f)) * log1pf(fabsf(dx));
  float acc[12];
#pragma unroll
  for (int hh = 0; hh < 12; hh++) acc[hh] = b2[hh];
  for (int c = 0; c < 384; c++) {
    float hv = w1[c * 2] * r0 + w1[c * 2 + 1] * r1 + b1[c];
    hv = fmaxf(hv, 0.f);
#pragma unroll
    for (int hh = 0; hh < 12; hh++) acc[hh] += hv * w2[hh * 384 + c];
  }
#pragma unroll
  for (int hh = 0; hh < 12; hh++) btab[(hh << 12) + p] = acc[hh];
}

__global__ __launch_bounds__(256) void cvt_kernel(
    const float* __restrict__ s, unsigned short* __restrict__ d, int n) {
  int i = blockIdx.x * 256 + threadIdx.x;
  if (i < n) d[i] = f2bf(s[i]);
}

// ---------------------------------------------------------------------------
extern "C" void kernel_launch(void* const* d_in, const int* in_sizes, int n_in,
                              void* d_out, int out_size, void* d_ws,
                              size_t ws_size, hipStream_t stream) {
  (void)in_sizes; (void)n_in; (void)out_size; (void)ws_size;
  const float* x      = (const float*)d_in[0];
  const float* qkv_w  = (const float*)d_in[1];
  const float* qkv_b  = (const float*)d_in[2];
  const float* proj_w = (const float*)d_in[3];
  const float* proj_b = (const float*)d_in[4];
  const float* mw1    = (const float*)d_in[5];
  const float* mb1    = (const float*)d_in[6];
  const float* mw2    = (const float*)d_in[7];
  const float* mb2    = (const float*)d_in[8];
  const float* lsc    = (const float*)d_in[9];
  const float* n1w    = (const float*)d_in[10];
  const float* n1b    = (const float*)d_in[11];
  const float* w1     = (const float*)d_in[12];
  const float* b1     = (const float*)d_in[13];
  const float* w2     = (const float*)d_in[14];
  const float* b2     = (const float*)d_in[15];
  const float* n2w    = (const float*)d_in[16];
  const float* n2b    = (const float*)d_in[17];

  char* ws = (char*)d_ws;
  unsigned short* wqb  = (unsigned short*)(ws + 0);
  unsigned short* wpb  = (unsigned short*)(ws + 884736);
  unsigned short* w1b  = (unsigned short*)(ws + 1179648);
  unsigned short* w2b  = (unsigned short*)(ws + 2359296);
  float* btab          = (float*)(ws + 3538944);
  unsigned short* xb   = (unsigned short*)(ws + 4194304);    // 101 MB
  unsigned short* qkvb = (unsigned short*)(ws + 104857600);  // 302 MB
  unsigned short* att  = (unsigned short*)(ws + 406847488);  // 101 MB
  unsigned short* hb   = (unsigned short*)(ws + 507510784);  // 101 MB
  unsigned short* projb = xb;    // reuse: xb dead after QKV GEMM
  unsigned short* y1b   = att;   // reuse: att dead after proj GEMM
  unsigned short* h2b   = qkvb;  // reuse: qkvb dead after attention
  float* yout = (float*)d_out;

  cvt_kernel<<<dim3(1728), 256, 0, stream>>>(qkv_w, wqb, 442368);
  cvt_kernel<<<dim3(576), 256, 0, stream>>>(proj_w, wpb, 147456);
  cvt_kernel<<<dim3(2304), 256, 0, stream>>>(w1, w1b, 589824);
  cvt_kernel<<<dim3(2304), 256, 0, stream>>>(w2, w2b, 589824);
  btab_kernel<<<dim3(16), 256, 0, stream>>>(mw1, mb1, mw2, mb2, btab);
  gather_cvt<<<dim3(32768), 256, 0, stream>>>(x, xb);

  // QKV: 131072 x 1152 x 384
  gemm_lds<0><<<dim3(9216), 256, 0, stream>>>(xb, wqb, qkv_b, qkvb, 1152, 384, 1024);
  // attention per (window, head)
  attn_win<<<dim3(2048, 12), 64, 0, stream>>>(qkvb, btab, lsc, att);
  // proj: 131072 x 384 x 384 -> bf16
  gemm_lds<0><<<dim3(3072), 256, 0, stream>>>(att, wpb, proj_b, projb, 384, 384, 1024);
  // LN1 + residual (+ ungather)
  ln1_kernel<<<dim3(32768), 256, 0, stream>>>(projb, x, n1w, n1b, yout, y1b);
  // MLP, chunked over M (4 x 32768 rows)
  for (int c = 0; c < 4; c++) {
    const unsigned short* ya = y1b + (size_t)c * 32768 * 384;
    unsigned short* h2c = h2b + (size_t)c * 32768 * 384;
    gemm_lds<1><<<dim3(3072), 256, 0, stream>>>(ya, w1b, b1, hb, 1536, 384, 256);
    gemm_lds<0><<<dim3(768), 256, 0, stream>>>(hb, w2b, b2, h2c, 384, 1536, 256);
  }
  // LN2 + residual
  ln2_kernel<<<dim3(32768), 256, 0, stream>>>(h2b, n2w, n2b, yout);
}

// Round 3
// 1336.785 us; speedup vs baseline: 1.3559x; 1.1365x over previous
//
#include <hip/hip_runtime.h>
#include <hip/hip_bf16.h>

typedef __attribute__((ext_vector_type(4))) float f32x4;
typedef __attribute__((ext_vector_type(4))) unsigned int u32x4;
typedef __attribute__((ext_vector_type(8))) __bf16 bf16x8;

#define DEV static __device__ __forceinline__

DEV unsigned short f2bf(float f) {
  unsigned u = __builtin_bit_cast(unsigned, f);
  u += 0x7fffu + ((u >> 16) & 1u);
  return (unsigned short)(u >> 16);
}
DEV float bf2f(unsigned short b) {
  return __builtin_bit_cast(float, ((unsigned)b) << 16);
}
DEV unsigned pk2(float a, float b) {
  return (unsigned)f2bf(a) | ((unsigned)f2bf(b) << 16);
}
DEV unsigned cvtpk(float lo, float hi) {
  unsigned r;
  asm("v_cvt_pk_bf16_f32 %0, %1, %2" : "=v"(r) : "v"(lo), "v"(hi));
  return r;
}
DEV float fexp2(float x) {
  float r;
  asm("v_exp_f32 %0, %1" : "=v"(r) : "v"(x));
  return r;
}
DEV f32x4 mfma16(u32x4 a, u32x4 b, f32x4 c) {
  return __builtin_amdgcn_mfma_f32_16x16x32_bf16(
      __builtin_bit_cast(bf16x8, a), __builtin_bit_cast(bf16x8, b), c, 0, 0, 0);
}
DEV float ssq8(u32x4 c) {
  float s = 0.f;
#pragma unroll
  for (int e = 0; e < 4; e++) {
    float lo = __builtin_bit_cast(float, c[e] << 16);
    float hi = __builtin_bit_cast(float, c[e] & 0xffff0000u);
    s += lo * lo + hi * hi;
  }
  return s;
}
DEV void gload16(const unsigned short* g, unsigned short* l) {
  __builtin_amdgcn_global_load_lds(
      (const __attribute__((address_space(1))) unsigned int*)g,
      (__attribute__((address_space(3))) unsigned int*)l, 16, 0, 0);
}

// ---------------------------------------------------------------------------
// bf16 GEMM: C = A[M][K] * B[N][K]^T + bias. EPI: 0 = bf16, 1 = gelu->bf16
// 128x128 tile, BK=64, global_load_lds + granule-XOR swizzle (both-sides).
// Requires K%64==0, N%128==0, grid%8==0.
// ---------------------------------------------------------------------------
template <int EPI>
__global__ __launch_bounds__(256) void gemm_lds(
    const unsigned short* __restrict__ A, const unsigned short* __restrict__ B,
    const float* __restrict__ bias, unsigned short* __restrict__ C,
    int N, int K, int mblocks) {
  __shared__ __align__(16) unsigned short As[128 * 64];
  __shared__ __align__(16) unsigned short Bs[128 * 64];
  const int nwg = gridDim.x, bid = blockIdx.x;
  const int swz = (bid & 7) * (nwg >> 3) + (bid >> 3);
  const int m0 = (swz % mblocks) * 128, n0 = (swz / mblocks) * 128;
  const int tid = threadIdx.x, w = tid >> 6, l = tid & 63;

  const int srow = w * 32 + (l >> 3);
  const int sg = ((l & 7) ^ ((l >> 3) & 7)) * 8;  // pre-swizzled src granule
  const unsigned short* ag = A + (size_t)(m0 + srow) * K + sg;
  const unsigned short* bg = B + (size_t)(n0 + srow) * K + sg;
  unsigned short* la = As + (w * 32) * 64;  // linear dest; HW adds lane*16
  unsigned short* lb = Bs + (w * 32) * 64;

  const int wm = (w >> 1) << 6, wn = (w & 1) << 6;
  const int lr = l & 15, lg = l >> 4;

  const f32x4 z4 = {0.f, 0.f, 0.f, 0.f};
  f32x4 acc[4][4];
#pragma unroll
  for (int i = 0; i < 4; i++)
#pragma unroll
    for (int j = 0; j < 4; j++) acc[i][j] = z4;

  for (int k0 = 0; k0 < K; k0 += 64) {
    __syncthreads();
#pragma unroll
    for (int i = 0; i < 4; i++) gload16(ag + (size_t)i * 8 * K + k0, la + i * 512);
#pragma unroll
    for (int i = 0; i < 4; i++) gload16(bg + (size_t)i * 8 * K + k0, lb + i * 512);
    __syncthreads();
#pragma unroll
    for (int ks = 0; ks < 2; ks++) {
      const int gsw = ((ks * 4 + lg) ^ (lr & 7)) * 8;
      u32x4 a[4], b[4];
#pragma unroll
      for (int i = 0; i < 4; i++)
        a[i] = *(const u32x4*)(As + (wm + i * 16 + lr) * 64 + gsw);
#pragma unroll
      for (int j = 0; j < 4; j++)
        b[j] = *(const u32x4*)(Bs + (wn + j * 16 + lr) * 64 + gsw);
#pragma unroll
      for (int i = 0; i < 4; i++)
#pragma unroll
        for (int j = 0; j < 4; j++) acc[i][j] = mfma16(a[i], b[j], acc[i][j]);
    }
  }

#pragma unroll
  for (int j = 0; j < 4; j++) {
    int ncol = n0 + wn + j * 16 + lr;
    float bv = bias[ncol];
#pragma unroll
    for (int i = 0; i < 4; i++) {
      int mbase = m0 + wm + i * 16 + lg * 4;
#pragma unroll
      for (int r = 0; r < 4; r++) {
        float v = acc[i][j][r] + bv;
        if (EPI == 1) v = 0.5f * v * (1.0f + erff(v * 0.70710678f));
        C[(size_t)(mbase + r) * N + ncol] = f2bf(v);
      }
    }
  }
}

// ---------------------------------------------------------------------------
// shift + window gather + fp32->bf16
// ---------------------------------------------------------------------------
__global__ __launch_bounds__(256) void gather_cvt(
    const float* __restrict__ x, unsigned short* __restrict__ xb) {
  int wv = threadIdx.x >> 6, l = threadIdx.x & 63;
  int m = blockIdx.x * 4 + wv;
  int w = m >> 6, t = m & 63;
  int b = w >> 6, wy = (w >> 3) & 7, wx = w & 7;
  int oy = (wy * 8 + (t >> 3) + 4) & 63;
  int ox = (wx * 8 + (t & 7) + 4) & 63;
  const float2* src =
      (const float2*)(x + (size_t)((((b << 6) | oy) << 6) | ox) * 384 + l * 6);
  float2 f0 = src[0], f1 = src[1], f2 = src[2];
  unsigned* dst = (unsigned*)(xb + (size_t)m * 384 + l * 6);
  dst[0] = pk2(f0.x, f0.y);
  dst[1] = pk2(f1.x, f1.y);
  dst[2] = pk2(f2.x, f2.y);
}

// ---------------------------------------------------------------------------
// Attention: 4 waves/block, wave = one head. Swapped QK^T, in-register
// softmax (exp2 domain, combined bias+mask table), in-register P repack.
// ---------------------------------------------------------------------------
__global__ __launch_bounds__(256, 4) void attn_win(
    const unsigned short* __restrict__ qkv, const float* __restrict__ btab2,
    const float* __restrict__ lscale, unsigned short* __restrict__ aout) {
  __shared__ __align__(16) unsigned short vT[4][32 * 72];
  __shared__ __align__(16) float rnk[4][64];
  const int w = blockIdx.x;
  const int wv = threadIdx.x >> 6, l = threadIdx.x & 63;
  const int h = blockIdx.y * 4 + wv;
  const int lr = l & 15, lg = l >> 4;
  const size_t base = (size_t)w * 64 * 1152 + h * 32;
  const f32x4 z4 = {0.f, 0.f, 0.f, 0.f};

  // V stage (transposed scatter), one k-row per lane
  {
    const u32x4* vp = (const u32x4*)(qkv + base + (size_t)l * 1152 + 768);
#pragma unroll
    for (int c4 = 0; c4 < 4; c4++) {
      u32x4 c = vp[c4];
#pragma unroll
      for (int e = 0; e < 4; e++) {
        vT[wv][(c4 * 8 + e * 2) * 72 + l] = (unsigned short)(c[e] & 0xffffu);
        vT[wv][(c4 * 8 + e * 2 + 1) * 72 + l] = (unsigned short)(c[e] >> 16);
      }
    }
  }
  // K fragments direct from global + row norms
  u32x4 kf[4];
#pragma unroll
  for (int tj = 0; tj < 4; tj++) {
    kf[tj] = *(const u32x4*)(qkv + base + (size_t)(tj * 16 + lr) * 1152 + 384 + lg * 8);
    float s = ssq8(kf[tj]);
    s += __shfl_xor(s, 16, 64);
    s += __shfl_xor(s, 32, 64);
    if (lg == 0) rnk[wv][tj * 16 + lr] = rsqrtf(fmaxf(s, 1e-24f));
  }
  // Q fragments + row norms (kept in registers)
  u32x4 qf[4];
  float rnq[4];
#pragma unroll
  for (int ti = 0; ti < 4; ti++) {
    qf[ti] = *(const u32x4*)(qkv + base + (size_t)(ti * 16 + lr) * 1152 + lg * 8);
    float s = ssq8(qf[ti]);
    s += __shfl_xor(s, 16, 64);
    s += __shfl_xor(s, 32, 64);
    rnq[ti] = rsqrtf(fmaxf(s, 1e-24f));
  }
  __syncthreads();

  u32x4 vb[2][2];
#pragma unroll
  for (int kc = 0; kc < 2; kc++)
#pragma unroll
    for (int tj2 = 0; tj2 < 2; tj2++)
      vb[kc][tj2] = *(const u32x4*)(&vT[wv][(tj2 * 16 + lr) * 72 + kc * 32 + lg * 8]);

  const float scl2 = expf(fminf(lscale[h], 4.6051702f)) * 1.44269504f;
  const int wt = ((((w >> 3) & 7) == 7) ? 2 : 0) | (((w & 7) == 7) ? 1 : 0);
  const float* tabh = btab2 + (((size_t)wt * 12 + h) << 12);
  const int s0l = lr + ((l & 16) ? 32 : 0);
  const int s1l = s0l + 16;
  const bool hi = (l & 32) != 0;

#pragma unroll
  for (int ti = 0; ti < 4; ti++) {
    // swapped QK^T: val[tj][r] = S[k=tj*16+lg*4+r][q=ti*16+lr]
    f32x4 sv[4];
#pragma unroll
    for (int tj = 0; tj < 4; tj++) sv[tj] = mfma16(kf[tj], qf[ti], z4);
    const float* tab = tabh + ((ti * 16 + lr) << 6);
    const float cb = rnq[ti] * scl2;
    f32x4 val[4];
    float m = -1e30f;
#pragma unroll
    for (int tj = 0; tj < 4; tj++) {
      f32x4 rk4 = *(const f32x4*)(&rnk[wv][tj * 16 + lg * 4]);
      f32x4 t4 = *(const f32x4*)(tab + tj * 16 + lg * 4);
#pragma unroll
      for (int r = 0; r < 4; r++) {
        float v = sv[tj][r] * (cb * rk4[r]) + t4[r];
        val[tj][r] = v;
        m = fmaxf(m, v);
      }
    }
    m = fmaxf(m, __shfl_xor(m, 16, 64));
    m = fmaxf(m, __shfl_xor(m, 32, 64));
    float den = 0.f;
#pragma unroll
    for (int tj = 0; tj < 4; tj++)
#pragma unroll
      for (int r = 0; r < 4; r++) {
        float p = fexp2(val[tj][r] - m);
        val[tj][r] = p;
        den += p;
      }
    den += __shfl_xor(den, 16, 64);
    den += __shfl_xor(den, 32, 64);
    float rden = 1.f / den;
#pragma unroll
    for (int tj = 0; tj < 4; tj++)
#pragma unroll
      for (int r = 0; r < 4; r++) val[tj][r] *= rden;

    // repack P to A-fragment layout: pa[kc] holds P[q=ti*16+lr][k=kc*32+8lg+e]
    f32x4 o[2] = {z4, z4};
#pragma unroll
    for (int kc = 0; kc < 2; kc++) {
      unsigned yA0 = cvtpk(val[2 * kc][0], val[2 * kc][1]);
      unsigned yA1 = cvtpk(val[2 * kc][2], val[2 * kc][3]);
      unsigned yB0 = cvtpk(val[2 * kc + 1][0], val[2 * kc + 1][1]);
      unsigned yB1 = cvtpk(val[2 * kc + 1][2], val[2 * kc + 1][3]);
      unsigned a0 = __shfl((int)yA0, s0l, 64), b0 = __shfl((int)yB0, s0l, 64);
      unsigned a1 = __shfl((int)yA1, s0l, 64), b1 = __shfl((int)yB1, s0l, 64);
      unsigned a2 = __shfl((int)yA0, s1l, 64), b2 = __shfl((int)yB0, s1l, 64);
      unsigned a3 = __shfl((int)yA1, s1l, 64), b3 = __shfl((int)yB1, s1l, 64);
      u32x4 pa = {hi ? b0 : a0, hi ? b1 : a1, hi ? b2 : a2, hi ? b3 : a3};
#pragma unroll
      for (int tj2 = 0; tj2 < 2; tj2++) o[tj2] = mfma16(pa, vb[kc][tj2], o[tj2]);
    }
    // out[q=ti*16+lg*4+r][d=tj2*16+lr]
#pragma unroll
    for (int tj2 = 0; tj2 < 2; tj2++)
#pragma unroll
      for (int r = 0; r < 4; r++)
        aout[(size_t)(w * 64 + ti * 16 + lg * 4 + r) * 384 + h * 32 + tj2 * 16 + lr] =
            f2bf(o[tj2][r]);
  }
}

// ---------------------------------------------------------------------------
// LN1: y1b = bf16(x + LN(proj gathered back))
// ---------------------------------------------------------------------------
__global__ __launch_bounds__(256) void ln1_kernel(
    const unsigned short* __restrict__ projb, const float* __restrict__ x,
    const float* __restrict__ nw, const float* __restrict__ nb,
    unsigned short* __restrict__ y1b) {
  int wv = threadIdx.x >> 6, l = threadIdx.x & 63;
  int n = blockIdx.x * 4 + wv;
  int b = n >> 12, y = (n >> 6) & 63, xx = n & 63;
  int sy = (y + 60) & 63, sx = (xx + 60) & 63;
  int m = ((((b << 6) | ((sy >> 3) << 3) | (sx >> 3)) << 6) |
           ((sy & 7) << 3) | (sx & 7));
  const unsigned* pr = (const unsigned*)(projb + (size_t)m * 384 + l * 6);
  unsigned u0 = pr[0], u1 = pr[1], u2 = pr[2];
  float v[6] = {bf2f((unsigned short)(u0 & 0xffffu)), bf2f((unsigned short)(u0 >> 16)),
                bf2f((unsigned short)(u1 & 0xffffu)), bf2f((unsigned short)(u1 >> 16)),
                bf2f((unsigned short)(u2 & 0xffffu)), bf2f((unsigned short)(u2 >> 16))};
  float sum = 0.f, ssq = 0.f;
#pragma unroll
  for (int c = 0; c < 6; c++) { sum += v[c]; ssq += v[c] * v[c]; }
#pragma unroll
  for (int d = 1; d < 64; d <<= 1) {
    sum += __shfl_xor(sum, d, 64);
    ssq += __shfl_xor(ssq, d, 64);
  }
  float mu = sum * (1.f / 384.f);
  float rstd = rsqrtf(ssq * (1.f / 384.f) - mu * mu + 1e-5f);
  const float2* xr = (const float2*)(x + (size_t)n * 384 + l * 6);
  float2 x0 = xr[0], x1 = xr[1], x2 = xr[2];
  float xv[6] = {x0.x, x0.y, x1.x, x1.y, x2.x, x2.y};
  float o[6];
#pragma unroll
  for (int c = 0; c < 6; c++) {
    int i = l * 6 + c;
    o[c] = xv[c] + (v[c] - mu) * rstd * nw[i] + nb[i];
  }
  unsigned* yb = (unsigned*)(y1b + (size_t)n * 384 + l * 6);
  yb[0] = pk2(o[0], o[1]);
  yb[1] = pk2(o[2], o[3]);
  yb[2] = pk2(o[4], o[5]);
}

// LN2: yout = y1 + LN(h2)   (f32 final output)
__global__ __launch_bounds__(256) void ln2_kernel(
    const unsigned short* __restrict__ y1b, const unsigned short* __restrict__ h2b,
    const float* __restrict__ nw, const float* __restrict__ nb,
    float* __restrict__ yout) {
  int wv = threadIdx.x >> 6, l = threadIdx.x & 63;
  int n = blockIdx.x * 4 + wv;
  const unsigned* hr = (const unsigned*)(h2b + (size_t)n * 384 + l * 6);
  unsigned u0 = hr[0], u1 = hr[1], u2 = hr[2];
  float v[6] = {bf2f((unsigned short)(u0 & 0xffffu)), bf2f((unsigned short)(u0 >> 16)),
                bf2f((unsigned short)(u1 & 0xffffu)), bf2f((unsigned short)(u1 >> 16)),
                bf2f((unsigned short)(u2 & 0xffffu)), bf2f((unsigned short)(u2 >> 16))};
  float sum = 0.f, ssq = 0.f;
#pragma unroll
  for (int c = 0; c < 6; c++) { sum += v[c]; ssq += v[c] * v[c]; }
#pragma unroll
  for (int d = 1; d < 64; d <<= 1) {
    sum += __shfl_xor(sum, d, 64);
    ssq += __shfl_xor(ssq, d, 64);
  }
  float mu = sum * (1.f / 384.f);
  float rstd = rsqrtf(ssq * (1.f / 384.f) - mu * mu + 1e-5f);
  const unsigned* yr = (const unsigned*)(y1b + (size_t)n * 384 + l * 6);
  unsigned y0 = yr[0], y1 = yr[1], y2 = yr[2];
  float yv[6] = {bf2f((unsigned short)(y0 & 0xffffu)), bf2f((unsigned short)(y0 >> 16)),
                 bf2f((unsigned short)(y1 & 0xffffu)), bf2f((unsigned short)(y1 >> 16)),
                 bf2f((unsigned short)(y2 & 0xffffu)), bf2f((unsigned short)(y2 >> 16))};
  float o[6];
#pragma unroll
  for (int c = 0; c < 6; c++) {
    int i = l * 6 + c;
    o[c] = yv[c] + (v[c] - mu) * rstd * nw[i] + nb[i];
  }
  float2* yo = (float2*)(yout + (size_t)n * 384 + l * 6);
  yo[0] = make_float2(o[0], o[1]);
  yo[1] = make_float2(o[2], o[3]);
  yo[2] = make_float2(o[4], o[5]);
}

// combined (bias + mask)*log2e table: btab2[wtype][h][q][k]
__global__ __launch_bounds__(256) void btab2_kernel(
    const float* __restrict__ w1, const float* __restrict__ b1,
    const float* __restrict__ w2, const float* __restrict__ b2,
    float* __restrict__ btab2) {
  int p = blockIdx.x * 256 + threadIdx.x;
  int i = p >> 6, j = p & 63;
  float dy = (float)((i >> 3) - (j >> 3));
  float dx = (float)((i & 7) - (j & 7));
  float r0 = (dy > 0.f ? 1.f : (dy < 0.f ? -1.f : 0.f)) * log1pf(fabsf(dy));
  float r1 = (dx > 0.f ? 1.f : (dx < 0.f ? -1.f : 0.f)) * log1pf(fabsf(dx));
  float acc[12];
#pragma unroll
  for (int hh = 0; hh < 12; hh++) acc[hh] = b2[hh];
  for (int c = 0; c < 384; c++) {
    float hv = w1[c * 2] * r0 + w1[c * 2 + 1] * r1 + b1[c];
    hv = fmaxf(hv, 0.f);
#pragma unroll
    for (int hh = 0; hh < 12; hh++) acc[hh] += hv * w2[hh * 384 + c];
  }
  bool ddy = ((i >> 3) >= 4) != ((j >> 3) >= 4);
  bool ddx = ((i & 7) >= 4) != ((j & 7) >= 4);
  const float L2E = 1.44269504f;
#pragma unroll
  for (int wt = 0; wt < 4; wt++) {
    float mask = ((((wt >> 1) != 0) && ddy) || (((wt & 1) != 0) && ddx)) ? -100.f : 0.f;
#pragma unroll
    for (int hh = 0; hh < 12; hh++)
      btab2[(((size_t)wt * 12 + hh) << 12) + p] = (acc[hh] + mask) * L2E;
  }
}

__global__ __launch_bounds__(256) void cvt_kernel(
    const float* __restrict__ s, unsigned short* __restrict__ d, int n) {
  int i = blockIdx.x * 256 + threadIdx.x;
  if (i < n) d[i] = f2bf(s[i]);
}

// ---------------------------------------------------------------------------
extern "C" void kernel_launch(void* const* d_in, const int* in_sizes, int n_in,
                              void* d_out, int out_size, void* d_ws,
                              size_t ws_size, hipStream_t stream) {
  (void)in_sizes; (void)n_in; (void)out_size; (void)ws_size;
  const float* x      = (const float*)d_in[0];
  const float* qkv_w  = (const float*)d_in[1];
  const float* qkv_b  = (const float*)d_in[2];
  const float* proj_w = (const float*)d_in[3];
  const float* proj_b = (const float*)d_in[4];
  const float* mw1    = (const float*)d_in[5];
  const float* mb1    = (const float*)d_in[6];
  const float* mw2    = (const float*)d_in[7];
  const float* mb2    = (const float*)d_in[8];
  const float* lsc    = (const float*)d_in[9];
  const float* n1w    = (const float*)d_in[10];
  const float* n1b    = (const float*)d_in[11];
  const float* w1     = (const float*)d_in[12];
  const float* b1     = (const float*)d_in[13];
  const float* w2     = (const float*)d_in[14];
  const float* b2     = (const float*)d_in[15];
  const float* n2w    = (const float*)d_in[16];
  const float* n2b    = (const float*)d_in[17];

  char* ws = (char*)d_ws;
  unsigned short* wqb  = (unsigned short*)(ws + 0);
  unsigned short* wpb  = (unsigned short*)(ws + 884736);
  unsigned short* w1b  = (unsigned short*)(ws + 1179648);
  unsigned short* w2b  = (unsigned short*)(ws + 2359296);
  float* btab2         = (float*)(ws + 3538944);             // 786 KB
  unsigned short* xb   = (unsigned short*)(ws + 4718592);    // 100.7 MB
  unsigned short* qkvb = (unsigned short*)(ws + 105381888);  // 302 MB
  unsigned short* att  = (unsigned short*)(ws + 407371776);  // 100.7 MB
  unsigned short* hb   = (unsigned short*)(ws + 508035072);  // 201 MB (chunk)
  unsigned short* projb = xb;    // xb dead after QKV GEMM
  unsigned short* y1b   = att;   // att dead after proj GEMM
  unsigned short* h2b   = qkvb;  // qkvb dead after attention
  float* yout = (float*)d_out;

  cvt_kernel<<<dim3(1728), 256, 0, stream>>>(qkv_w, wqb, 442368);
  cvt_kernel<<<dim3(576), 256, 0, stream>>>(proj_w, wpb, 147456);
  cvt_kernel<<<dim3(2304), 256, 0, stream>>>(w1, w1b, 589824);
  cvt_kernel<<<dim3(2304), 256, 0, stream>>>(w2, w2b, 589824);
  btab2_kernel<<<dim3(16), 256, 0, stream>>>(mw1, mb1, mw2, mb2, btab2);
  gather_cvt<<<dim3(32768), 256, 0, stream>>>(x, xb);

  // QKV: 131072 x 1152 x 384
  gemm_lds<0><<<dim3(9216), 256, 0, stream>>>(xb, wqb, qkv_b, qkvb, 1152, 384, 1024);
  // attention: 4 heads/block
  attn_win<<<dim3(2048, 3), 256, 0, stream>>>(qkvb, btab2, lsc, att);
  // proj: 131072 x 384 x 384
  gemm_lds<0><<<dim3(3072), 256, 0, stream>>>(att, wpb, proj_b, projb, 384, 384, 1024);
  // LN1 + residual (+ ungather) -> bf16 only
  ln1_kernel<<<dim3(32768), 256, 0, stream>>>(projb, x, n1w, n1b, y1b);
  // MLP, 2 chunks of 65536 rows
  for (int c = 0; c < 2; c++) {
    const unsigned short* ya = y1b + (size_t)c * 65536 * 384;
    unsigned short* h2c = h2b + (size_t)c * 65536 * 384;
    gemm_lds<1><<<dim3(6144), 256, 0, stream>>>(ya, w1b, b1, hb, 1536, 384, 512);
    gemm_lds<0><<<dim3(1536), 256, 0, stream>>>(hb, w2b, b2, h2c, 384, 1536, 512);
  }
  // LN2 + residual -> f32 output
  ln2_kernel<<<dim3(32768), 256, 0, stream>>>(y1b, h2b, n2w, n2b, yout);
}